// Round 10
// baseline (8378.488 us; speedup 1.0000x reference)
//
#include <hip/hip_runtime.h>
#include <cstdint>
#include <cstddef>

// LSTM B=128 T=512 I=H=1024. fp32 in/out, bf16 MFMA internally.
// R10: FUSED single-dispatch recurrence. Each of 256 blocks (8 groups x 32
// col-blocks) computes BOTH gate GEMMs per step: gates = x_t@Winp + h@Whp
// + bias, with Winp AND Whp slices resident in VGPRs (64+64 regs). No
// separate xp GEMM, no xp buffer, no chunking. x is pre-packed by
// convert_xf into MFMA-fragment-order granules so the per-step x-tile is
// one coalesced 32KB read (issued before the h-poll -> latency hidden).
// Sync = R8's proven scheme: producers publish h via agent-scope 8B
// atomic exchanges; consumer line-owners sparse-RMW-poll granule 0 of
// their 64B line (detection == data at the coherence point), plain-AL the
// rest, per-granule RMW fallback. Sentinel 0xFFFF (bf16 NaN) impossible
// as real h. Ring: 513 slots, slot t = h_t, pre-sentineled by memset.

#define B_  128
#define T_  512
#define I_  1024
#define H_  1024
#define G4_ 4096
#define SLOTG 32768ull   // u64 granules per h slot (128*1024*2B / 8)

typedef __attribute__((ext_vector_type(8))) short short8;   // 8 bf16
typedef __attribute__((ext_vector_type(4))) float f32x4;
typedef __attribute__((ext_vector_type(2))) unsigned long long u64x2;
typedef unsigned long long u64;

static __device__ __forceinline__ unsigned short f2bf(float f) {
    unsigned u = __builtin_bit_cast(unsigned, f);
    u += 0x7fffu + ((u >> 16) & 1u);          // RNE (finite inputs)
    return (unsigned short)(u >> 16);
}
static __device__ __forceinline__ float sigm(float x) {
    return 1.0f / (1.0f + exp2f(-1.4426950408889634f * x));
}
static __device__ __forceinline__ float tanh_(float x) {
    float e = exp2f(2.8853900817779268f * x);  // exp(2x)
    return 1.0f - 2.0f / (e + 1.0f);
}
static __device__ __forceinline__ f32x4 mfma16(short8 a, short8 b, f32x4 c) {
    return __builtin_amdgcn_mfma_f32_16x16x32_bf16(a, b, c, 0, 0, 0);
}
static __device__ __forceinline__ u64 ffbits(u64 v) {
    return ((~v) - 0x0001000100010001ull) & v & 0x8000800080008000ull;
}
#define AL(p)   __hip_atomic_load((p), __ATOMIC_RELAXED, __HIP_MEMORY_SCOPE_AGENT)
#define ARMW(p) __hip_atomic_fetch_add((p), 0ull, __ATOMIC_RELAXED, __HIP_MEMORY_SCOPE_AGENT)

// ---- pack all 8 weights: z 0-3 = W_x gates -> Winp, z 4-7 = W_h -> Whp ----
__global__ __launch_bounds__(256) void pack_w8(
    const float* w0, const float* w1, const float* w2, const float* w3,
    const float* w4, const float* w5, const float* w6, const float* w7,
    unsigned short* __restrict__ Winp, unsigned short* __restrict__ Whp) {
    const float* ws[8] = {w0, w1, w2, w3, w4, w5, w6, w7};
    const float* W = ws[blockIdx.z];
    unsigned short* dst = (blockIdx.z < 4) ? Winp : Whp;
    const int g = blockIdx.z & 3;
    __shared__ float tile[64][65];
    const int tid = threadIdx.x;
    const int k0 = blockIdx.y * 64;
    const int j0 = blockIdx.x * 64;
    {
        const int r  = tid >> 2;
        const int c0 = (tid & 3) * 16;
        const float* src = W + (size_t)(k0 + r) * H_ + j0 + c0;
        #pragma unroll
        for (int q = 0; q < 4; ++q) {
            float4 v = *(const float4*)(src + q * 4);
            tile[r][c0 + q*4 + 0] = v.x;
            tile[r][c0 + q*4 + 1] = v.y;
            tile[r][c0 + q*4 + 2] = v.z;
            tile[r][c0 + q*4 + 3] = v.w;
        }
    }
    __syncthreads();
    {
        const int jl   = tid >> 2;
        const int kseg = (tid & 3) * 16;
        unsigned short* orow = dst + ((size_t)(j0 + jl) * 4 + g) * 1024 + (k0 + kseg);
        #pragma unroll
        for (int q = 0; q < 16; q += 4) {
            ushort4 u;
            u.x = f2bf(tile[kseg + q + 0][jl]);
            u.y = f2bf(tile[kseg + q + 1][jl]);
            u.z = f2bf(tile[kseg + q + 2][jl]);
            u.w = f2bf(tile[kseg + q + 3][jl]);
            *(ushort4*)(orow + q) = u;
        }
    }
}

__global__ __launch_bounds__(256) void pack_bias(
    const float* b0x, const float* b0h, const float* b1x, const float* b1h,
    const float* b2x, const float* b2h, const float* b3x, const float* b3h,
    float* __restrict__ out) {
    int jc = blockIdx.x * 256 + threadIdx.x;
    int g = jc & 3, jh = jc >> 2;
    const float* bx = (g == 0) ? b0x : (g == 1) ? b1x : (g == 2) ? b2x : b3x;
    const float* bh = (g == 0) ? b0h : (g == 1) ? b1h : (g == 2) ? b2h : b3h;
    out[jc] = bx[jh] + bh[jh];
}

// ---- x fp32 -> fragment-order bf16 granules ----
// xbf layout: tile (t, grp) = 2048 granules of 16B; granule g = ko*16 + row
// (ko = k/8 in [0,128), row in [0,16)). Block = one tile; LDS transpose.
__global__ __launch_bounds__(256) void convert_xf(
    const float* __restrict__ x, unsigned short* __restrict__ xbf) {
    __shared__ unsigned short ld[16][1032];
    const int tid = threadIdx.x;
    const int tt = blockIdx.x;                 // timestep
    const int grp = blockIdx.y;
    {
        const int row = tid >> 4, seg = tid & 15;
        const float* src = x + ((size_t)(grp * 16 + row) * T_ + tt) * I_ + seg * 64;
        #pragma unroll
        for (int q = 0; q < 4; ++q) {
            float4 a = *(const float4*)(src + q * 16);
            float4 b = *(const float4*)(src + q * 16 + 4);
            float4 c = *(const float4*)(src + q * 16 + 8);
            float4 d = *(const float4*)(src + q * 16 + 12);
            ushort4 u0; u0.x = f2bf(a.x); u0.y = f2bf(a.y); u0.z = f2bf(a.z); u0.w = f2bf(a.w);
            ushort4 u1; u1.x = f2bf(b.x); u1.y = f2bf(b.y); u1.z = f2bf(b.z); u1.w = f2bf(b.w);
            ushort4 u2; u2.x = f2bf(c.x); u2.y = f2bf(c.y); u2.z = f2bf(c.z); u2.w = f2bf(c.w);
            ushort4 u3; u3.x = f2bf(d.x); u3.y = f2bf(d.y); u3.z = f2bf(d.z); u3.w = f2bf(d.w);
            unsigned short* dl = &ld[row][seg * 64 + q * 16];
            *(ushort4*)(dl + 0)  = u0;
            *(ushort4*)(dl + 4)  = u1;
            *(ushort4*)(dl + 8)  = u2;
            *(ushort4*)(dl + 12) = u3;
        }
    }
    __syncthreads();
    {   // store granules g = tid*8 .. +8 (128B contiguous per thread)
        unsigned short* dst = xbf + (((size_t)tt * 8 + grp) * 2048 + (size_t)tid * 8) * 8;
        #pragma unroll
        for (int j = 0; j < 8; ++j) {
            int g = tid * 8 + j;
            int row2 = g & 15, ko = g >> 4;
            *(uint4*)(dst + j * 8) = *(const uint4*)&ld[row2][ko * 8];
        }
    }
}

// ---- fused recurrence: grid 256 x 1024 thr, ONE dispatch for 512 steps.
// grp = bx>>5 (16 batch rows), cb = bx&31 (128 packed gate-cols).
// wave w: cq = w&3 (32 cols), kq = w>>2 (K quarter). Per step per wave:
// 8 ks x {h-MFMA x2, x-MFMA x2} accumulating gates in fp32.
__global__ __launch_bounds__(1024, 4) void lstm_recur(
    const unsigned short* __restrict__ Whp,
    const unsigned short* __restrict__ Wip,
    const unsigned short* __restrict__ xbf,    // [512][8][2048] granules
    const float* __restrict__ bias,            // [4096] packed
    u64* __restrict__ hring,                   // 513 slots; slot t = h_t
    float* __restrict__ outp) {                // d_out [h|c] fp32
    __shared__ __align__(16) char hlds[32768];     // fragment-order h tile
    __shared__ __align__(16) char xlds[32768];     // fragment-order x tile
    __shared__ __align__(16) float gl[4][16][132]; // per-kq partial gates

    const int t = threadIdx.x;
    const int l = t & 63, w = t >> 6;
    const int l15 = l & 15, hi = l >> 4;
    const int cq = w & 3, kq = w >> 2;
    const int grp = blockIdx.x >> 5, cb = blockIdx.x & 31;
    const int row0 = grp * 16;

    // resident weights: Whp + Winp slices, 2 col-tiles x 8 ksteps each
    short8 wfh[2][8], wfx[2][8];
    {
        const unsigned short* wb = Whp + (size_t)(cb * 128 + cq * 32 + l15) * 1024
                                       + kq * 256 + hi * 8;
        const unsigned short* wc = Wip + (size_t)(cb * 128 + cq * 32 + l15) * 1024
                                       + kq * 256 + hi * 8;
        #pragma unroll
        for (int ci = 0; ci < 2; ++ci)
            #pragma unroll
            for (int ks = 0; ks < 8; ++ks) {
                wfh[ci][ks] = *(const short8*)(wb + ci * 16 * 1024 + ks * 32);
                wfx[ci][ks] = *(const short8*)(wc + ci * 16 * 1024 + ks * 32);
            }
    }

    const int urow = t >> 5, ujh = t & 31;     // update mapping (t<512)
    float creg = 0.f;
    float4 ub = {0.f, 0.f, 0.f, 0.f};
    if (t < 512) ub = *(const float4*)&bias[cb * 128 + ujh * 4];

    const int prow = t & 15, lq = t >> 4;      // h 64B-line owner (t<512)

    for (int st = 0; st < T_; ++st) {
        // x tile loads: coalesced 16B/lane, issued before the h-poll
        const unsigned short* xt = xbf + ((size_t)st * 8 + grp) * 2048 * 8;
        uint4 xg0 = *(const uint4*)(xt + (size_t)t * 8);
        uint4 xg1 = *(const uint4*)(xt + (size_t)(1024 + t) * 8);

        // sparse-RMW poll of own 64B line of h_t (detection == data)
        if (t < 512) {
            u64 q[8];
            u64* rp = hring + (size_t)st * SLOTG + (size_t)(row0 + prow) * 256 + lq * 8;
            q[0] = ARMW(rp);
            while (ffbits(q[0])) {
                __builtin_amdgcn_s_sleep(1);
                q[0] = ARMW(rp);
            }
            q[1] = AL(rp + 1); q[2] = AL(rp + 2); q[3] = AL(rp + 3);
            q[4] = AL(rp + 4); q[5] = AL(rp + 5); q[6] = AL(rp + 6); q[7] = AL(rp + 7);
            u64 bad = ffbits(q[1]) | ffbits(q[2]) | ffbits(q[3]) | ffbits(q[4])
                    | ffbits(q[5]) | ffbits(q[6]) | ffbits(q[7]);
            while (bad) {              // rare: publish burst not fully landed
                __builtin_amdgcn_s_sleep(1);
                q[1] = ARMW(rp + 1); q[2] = ARMW(rp + 2); q[3] = ARMW(rp + 3);
                q[4] = ARMW(rp + 4); q[5] = ARMW(rp + 5); q[6] = ARMW(rp + 6);
                q[7] = ARMW(rp + 7);
                bad = ffbits(q[1]) | ffbits(q[2]) | ffbits(q[3]) | ffbits(q[4])
                    | ffbits(q[5]) | ffbits(q[6]) | ffbits(q[7]);
            }
            #pragma unroll
            for (int j = 0; j < 4; ++j) {
                u64x2 v = {q[2 * j], q[2 * j + 1]};
                *(u64x2*)(hlds + ((lq * 4 + j) * 16 + prow) * 16) = v;
            }
        }
        // stage x (all 1024 threads, lane-contiguous b128 -> conflict-free)
        *(uint4*)(xlds + t * 16) = xg0;
        *(uint4*)(xlds + (1024 + t) * 16) = xg1;
        __syncthreads();

        // both GEMMs: lane-contiguous A reads, resident B fragments
        f32x4 acc0 = {}, acc1 = {};
        #pragma unroll
        for (int ks = 0; ks < 8; ++ks) {
            int ko = (kq * 8 + ks) * 4 + hi;
            short8 ha = *(const short8*)(hlds + ko * 256 + l15 * 16);
            short8 xa = *(const short8*)(xlds + ko * 256 + l15 * 16);
            acc0 = mfma16(ha, wfh[0][ks], acc0);
            acc1 = mfma16(ha, wfh[1][ks], acc1);
            acc0 = mfma16(xa, wfx[0][ks], acc0);
            acc1 = mfma16(xa, wfx[1][ks], acc1);
        }
        #pragma unroll
        for (int j = 0; j < 4; ++j) {
            gl[kq][hi * 4 + j][cq * 32 + l15]      = acc0[j];
            gl[kq][hi * 4 + j][cq * 32 + 16 + l15] = acc1[j];
        }
        __syncthreads();

        // update (t<512, one cell each) + packed publish via shfl
        if (t < 512) {
            float4 s = *(const float4*)&gl[0][urow][ujh * 4];
            #pragma unroll
            for (int k2 = 1; k2 < 4; ++k2) {
                float4 s2 = *(const float4*)&gl[k2][urow][ujh * 4];
                s.x += s2.x; s.y += s2.y; s.z += s2.z; s.w += s2.w;
            }
            float gi = s.x + ub.x;
            float gf = s.y + ub.y;
            float gg = s.z + ub.z;
            float go = s.w + ub.w;
            float it_ = sigm(gi), ft = sigm(gf), gt = tanh_(gg), ot = sigm(go);
            float cn = ft * creg + it_ * gt;
            float hn = ot * tanh_(cn);
            creg = cn;
            if (st == T_ - 1) {
                size_t o = (size_t)(row0 + urow) * H_ + cb * 32 + ujh;
                outp[o] = hn;
                outp[(size_t)B_ * H_ + o] = cn;
            } else {
                unsigned hb = (unsigned)f2bf(hn);
                unsigned ob = __shfl_xor(hb, 1);
                unsigned v01 = (l & 1) ? (ob | (hb << 16)) : (hb | (ob << 16));
                unsigned v23 = __shfl_xor(v01, 2);
                if ((t & 3) == 0) {
                    u64 hw = (u64)v01 | ((u64)v23 << 32);
                    u64* wp = hring + (size_t)(st + 1) * SLOTG
                            + (size_t)(row0 + urow) * 256 + cb * 8 + (ujh >> 2);
                    (void)__hip_atomic_exchange(wp, hw, __ATOMIC_RELAXED,
                                                __HIP_MEMORY_SCOPE_AGENT);
                }
            }
        }
        // no trailing barrier: hlds/xlds reads done before barrier-2; gl
        // rewritten only after next barrier-1.
    }
}

extern "C" void kernel_launch(void* const* d_in, const int* in_sizes, int n_in,
                              void* d_out, int out_size, void* d_ws, size_t ws_size,
                              hipStream_t stream) {
    const float* x = (const float*)d_in[0];
    const float* Wx[4] = {(const float*)d_in[1], (const float*)d_in[3],
                          (const float*)d_in[5], (const float*)d_in[7]};
    const float* Wh[4] = {(const float*)d_in[2], (const float*)d_in[4],
                          (const float*)d_in[6], (const float*)d_in[8]};
    const float* bx[4] = {(const float*)d_in[9],  (const float*)d_in[11],
                          (const float*)d_in[13], (const float*)d_in[15]};
    const float* bh[4] = {(const float*)d_in[10], (const float*)d_in[12],
                          (const float*)d_in[14], (const float*)d_in[16]};

    char* p = (char*)d_ws;
    auto take = [&](size_t bytes) {
        char* q = p; p += (bytes + 255) & ~(size_t)255; return q;
    };
    unsigned short* Winp = (unsigned short*)take((size_t)G4_ * 1024 * 2);
    unsigned short* Whp  = (unsigned short*)take((size_t)G4_ * 1024 * 2);
    float*          bias = (float*)take(G4_ * 4);
    unsigned short* xbf  = (unsigned short*)take((size_t)T_ * 8 * 2048 * 16);
    u64*            hring = (u64*)take((size_t)(T_ + 1) * SLOTG * 8);

    pack_w8<<<dim3(16, 16, 8), 256, 0, stream>>>(
        Wx[0], Wx[1], Wx[2], Wx[3], Wh[0], Wh[1], Wh[2], Wh[3], Winp, Whp);
    pack_bias<<<16, 256, 0, stream>>>(bx[0], bh[0], bx[1], bh[1],
                                      bx[2], bh[2], bx[3], bh[3], bias);
    convert_xf<<<dim3(T_, 8), 256, 0, stream>>>(x, xbf);
    (void)hipMemsetAsync(hring, 0, SLOTG * 8, stream);              // h0 = 0
    (void)hipMemsetAsync(hring + SLOTG, 0xFF,
                         (size_t)T_ * SLOTG * 8, stream);           // sentinels

    lstm_recur<<<256, 1024, 0, stream>>>(Whp, Winp, xbf, bias, hring,
                                         (float*)d_out);
}

// Round 11
// 5517.961 us; speedup vs baseline: 1.5184x; 1.5184x over previous
//
#include <hip/hip_runtime.h>
#include <cstdint>
#include <cstddef>

// LSTM B=128 T=512 I=H=1024. fp32 in/out, bf16 MFMA internally.
// R11: split pipeline (convert_x -> gemm_xproj -> lstm_recur) with
// XCD-LOCAL recurrence sync. grp = blockIdx.x & 7 puts all 32 blocks of a
// batch-row group on ONE XCD (round-robin dispatch, measured m09): h
// publish = volatile plain store (write-through into the shared XCD L2,
// ~200cy visibility) + agent-scope atomic exchange to LLC as backup.
// Consumers poll their own 64B line with relaxed agent atomic loads
// (L1-bypass, L2-served — R5/R6/R8 evidence); after 64 rounds fall back
// to LLC RMWs, so a different XCD mapping degrades speed, not correctness.
// Sentinel 0xFFFF (bf16 NaN) impossible as real h (|h|<1 finite).

#define B_  128
#define T_  512
#define I_  1024
#define H_  1024
#define G4_ 4096
#define SLOTG 32768ull   // u64 granules per h slot (128*1024*2B / 8)

typedef __attribute__((ext_vector_type(8))) short short8;   // 8 bf16
typedef __attribute__((ext_vector_type(4))) float f32x4;
typedef __attribute__((ext_vector_type(2))) unsigned long long u64x2;
typedef unsigned long long u64;

static __device__ __forceinline__ unsigned short f2bf(float f) {
    unsigned u = __builtin_bit_cast(unsigned, f);
    u += 0x7fffu + ((u >> 16) & 1u);          // RNE (finite inputs)
    return (unsigned short)(u >> 16);
}
static __device__ __forceinline__ float bf2f(unsigned short s) {
    unsigned u = (unsigned)s << 16;
    return __builtin_bit_cast(float, u);
}
static __device__ __forceinline__ float sigm(float x) {
    return 1.0f / (1.0f + exp2f(-1.4426950408889634f * x));
}
static __device__ __forceinline__ float tanh_(float x) {
    float e = exp2f(2.8853900817779268f * x);  // exp(2x)
    return 1.0f - 2.0f / (e + 1.0f);
}
static __device__ __forceinline__ f32x4 mfma16(short8 a, short8 b, f32x4 c) {
    return __builtin_amdgcn_mfma_f32_16x16x32_bf16(a, b, c, 0, 0, 0);
}
static __device__ __forceinline__ u64 ffbits(u64 v) {
    return ((~v) - 0x0001000100010001ull) & v & 0x8000800080008000ull;
}
#define AL(p)   __hip_atomic_load((p), __ATOMIC_RELAXED, __HIP_MEMORY_SCOPE_AGENT)
#define ARMW(p) __hip_atomic_fetch_add((p), 0ull, __ATOMIC_RELAXED, __HIP_MEMORY_SCOPE_AGENT)

// ---- pack all 8 weights: z 0-3 = W_x gates -> Winp, z 4-7 = W_h -> Whp ----
__global__ __launch_bounds__(256) void pack_w8(
    const float* w0, const float* w1, const float* w2, const float* w3,
    const float* w4, const float* w5, const float* w6, const float* w7,
    unsigned short* __restrict__ Winp, unsigned short* __restrict__ Whp) {
    const float* ws[8] = {w0, w1, w2, w3, w4, w5, w6, w7};
    const float* W = ws[blockIdx.z];
    unsigned short* dst = (blockIdx.z < 4) ? Winp : Whp;
    const int g = blockIdx.z & 3;
    __shared__ float tile[64][65];
    const int tid = threadIdx.x;
    const int k0 = blockIdx.y * 64;
    const int j0 = blockIdx.x * 64;
    {
        const int r  = tid >> 2;
        const int c0 = (tid & 3) * 16;
        const float* src = W + (size_t)(k0 + r) * H_ + j0 + c0;
        #pragma unroll
        for (int q = 0; q < 4; ++q) {
            float4 v = *(const float4*)(src + q * 4);
            tile[r][c0 + q*4 + 0] = v.x;
            tile[r][c0 + q*4 + 1] = v.y;
            tile[r][c0 + q*4 + 2] = v.z;
            tile[r][c0 + q*4 + 3] = v.w;
        }
    }
    __syncthreads();
    {
        const int jl   = tid >> 2;
        const int kseg = (tid & 3) * 16;
        unsigned short* orow = dst + ((size_t)(j0 + jl) * 4 + g) * 1024 + (k0 + kseg);
        #pragma unroll
        for (int q = 0; q < 16; q += 4) {
            ushort4 u;
            u.x = f2bf(tile[kseg + q + 0][jl]);
            u.y = f2bf(tile[kseg + q + 1][jl]);
            u.z = f2bf(tile[kseg + q + 2][jl]);
            u.w = f2bf(tile[kseg + q + 3][jl]);
            *(ushort4*)(orow + q) = u;
        }
    }
}

__global__ __launch_bounds__(256) void pack_bias(
    const float* b0x, const float* b0h, const float* b1x, const float* b1h,
    const float* b2x, const float* b2h, const float* b3x, const float* b3h,
    float* __restrict__ out) {
    int jc = blockIdx.x * 256 + threadIdx.x;
    int g = jc & 3, jh = jc >> 2;
    const float* bx = (g == 0) ? b0x : (g == 1) ? b1x : (g == 2) ? b2x : b3x;
    const float* bh = (g == 0) ? b0h : (g == 1) ? b1h : (g == 2) ? b2h : b3h;
    out[jc] = bx[jh] + bh[jh];
}

// ---- x fp32 -> xb bf16, chunk-local rows r = b*Tcc+tc ----
__global__ __launch_bounds__(256) void convert_x(const float* __restrict__ x,
                                                 unsigned short* __restrict__ xb,
                                                 int t0, int Tcc) {
    int e = blockIdx.x * 256 + threadIdx.x;
    int i = (e & 127) << 3;
    int r = e >> 7;
    int b = r / Tcc, tc = r - b * Tcc;
    const float* s = x + (size_t)(b * T_ + t0 + tc) * I_ + i;
    float4 v0 = *(const float4*)s;
    float4 v1 = *(const float4*)(s + 4);
    ushort4 u0; u0.x = f2bf(v0.x); u0.y = f2bf(v0.y); u0.z = f2bf(v0.z); u0.w = f2bf(v0.w);
    ushort4 u1; u1.x = f2bf(v1.x); u1.y = f2bf(v1.y); u1.z = f2bf(v1.z); u1.w = f2bf(v1.w);
    unsigned short* d = xb + (size_t)r * I_ + i;
    *(ushort4*)d = u0;
    *(ushort4*)(d + 4) = u1;
}

// ---- xp(bf16) = xb @ Winp + bias; LDS-transposed epilogue ----
// grid (16, 2*Tcc); 4 waves: 64 rows x 64 cols each (block: 64r x 256c).
__global__ __launch_bounds__(256) void gemm_xproj(
    const unsigned short* __restrict__ A,      // xb [128*Tcc][1024]
    const unsigned short* __restrict__ Bt,
    const float* __restrict__ bias,
    unsigned short* __restrict__ xp,           // [Tcc][128][4096] bf16
    int Tcc) {
    __shared__ unsigned short ot[64][256];     // 32KB epilogue stage
    const int tid = threadIdx.x;
    const int w = tid >> 6, l = tid & 63;
    const int l15 = l & 15, hi = l >> 4;
    const int row0 = blockIdx.y * 64;
    const int col0 = blockIdx.x * 256 + w * 64;
    f32x4 acc[4][4] = {};
    const unsigned short* a0 = A  + (size_t)(row0 + l15) * 1024 + hi * 8;
    const unsigned short* b0 = Bt + (size_t)(col0 + l15) * 1024 + hi * 8;
    for (int ks = 0; ks < 1024; ks += 32) {
        short8 a[4], bb[4];
        #pragma unroll
        for (int mi = 0; mi < 4; ++mi) a[mi]  = *(const short8*)(a0 + (size_t)mi * 16 * 1024 + ks);
        #pragma unroll
        for (int ni = 0; ni < 4; ++ni) bb[ni] = *(const short8*)(b0 + (size_t)ni * 16 * 1024 + ks);
        #pragma unroll
        for (int mi = 0; mi < 4; ++mi)
            #pragma unroll
            for (int ni = 0; ni < 4; ++ni)
                acc[mi][ni] = mfma16(a[mi], bb[ni], acc[mi][ni]);
    }
    #pragma unroll
    for (int mi = 0; mi < 4; ++mi) {
        #pragma unroll
        for (int ni = 0; ni < 4; ++ni) {
            float bs = bias[col0 + ni * 16 + l15];
            #pragma unroll
            for (int j = 0; j < 4; ++j)
                ot[mi * 16 + hi * 4 + j][w * 64 + ni * 16 + l15] =
                    f2bf(acc[mi][ni][j] + bs);
        }
    }
    __syncthreads();
    {   // coalesced xp store: thread -> (row rl, 128B chunk)
        const int rl = tid >> 2, ch = tid & 3;
        int r = row0 + rl;
        int b = r / Tcc, tc = r - b * Tcc;
        unsigned short* dst = xp + (size_t)(tc * 128 + b) * G4_
                            + blockIdx.x * 256 + ch * 64;
        const unsigned short* src = &ot[rl][ch * 64];
        #pragma unroll
        for (int q = 0; q < 8; ++q)
            *(uint4*)(dst + q * 8) = *(const uint4*)(src + q * 8);
    }
}

// ---- recurrence: grid 256 x 1024 thr. grp = bx&7 (XCD-local!), cb = bx>>3.
// wave w: cq = w&3 (32 cols), kq = w>>2 (K quarter, 8 ksteps of 32).
__global__ __launch_bounds__(1024, 4) void lstm_recur(
    const unsigned short* __restrict__ Whp,
    const unsigned short* __restrict__ xp,     // [Tcc][128][4096] bf16
    u64* __restrict__ hring,                   // Tc+1 slots; slot0 = carry
    float* __restrict__ cbuf,                  // [128][1024] fp32 in/out
    float* __restrict__ outp,                  // d_out [h|c] fp32
    int Tcc, int is_last) {
    __shared__ __align__(16) char hlds[32768];     // fragment-order h tile
    __shared__ __align__(16) float gl[4][16][132]; // per-kq partial gates

    const int t = threadIdx.x;
    const int l = t & 63, w = t >> 6;
    const int l15 = l & 15, hi = l >> 4;
    const int cq = w & 3, kq = w >> 2;
    const int grp = blockIdx.x & 7;            // same-XCD group (round-robin)
    const int cb  = blockIdx.x >> 3;           // packed cols cb*128..+127
    const int row0 = grp * 16;

    // resident W_h: 2 col-tiles x 8 ksteps = 64 regs
    short8 wf[2][8];
    {
        const unsigned short* wb = Whp + (size_t)(cb * 128 + cq * 32 + l15) * 1024
                                       + kq * 256 + hi * 8;
        #pragma unroll
        for (int ci = 0; ci < 2; ++ci)
            #pragma unroll
            for (int ks = 0; ks < 8; ++ks)
                wf[ci][ks] = *(const short8*)(wb + ci * 16 * 1024 + ks * 32);
    }

    const int urow = t >> 5, ujh = t & 31;     // update mapping (t<512)
    float creg = 0.f;
    if (t < 512) creg = cbuf[(size_t)(row0 + urow) * H_ + cb * 32 + ujh];

    const int prow = t & 15, lq = t >> 4;      // h 64B-line owner (t<512)

    for (int st = 0; st < Tcc; ++st) {
        // xp prefetch (independent of h) — overlaps the data poll
        ushort4 xv = {0, 0, 0, 0};
        if (t < 512)
            xv = *(const ushort4*)(xp + ((size_t)st * 128 + row0 + urow) * G4_
                                      + cb * 128 + ujh * 4);

        // poll own 64B line of h_t: relaxed ALs (local-XCD L2 fast path);
        // LLC RMW fallback after 64 rounds (wrong-mapping safety)
        if (t < 512) {
            u64 q[8];
            u64* rp = hring + (size_t)st * SLOTG + (size_t)(row0 + prow) * 256 + lq * 8;
            int it = 0;
            q[0] = AL(rp);
            while (ffbits(q[0])) {
                ++it;
                __builtin_amdgcn_s_sleep(1);
                q[0] = (it < 64) ? AL(rp) : ARMW(rp);
            }
            q[1] = AL(rp + 1); q[2] = AL(rp + 2); q[3] = AL(rp + 3);
            q[4] = AL(rp + 4); q[5] = AL(rp + 5); q[6] = AL(rp + 6); q[7] = AL(rp + 7);
            u64 bad = ffbits(q[1]) | ffbits(q[2]) | ffbits(q[3]) | ffbits(q[4])
                    | ffbits(q[5]) | ffbits(q[6]) | ffbits(q[7]);
            int it2 = 0;
            while (bad) {
                ++it2;
                __builtin_amdgcn_s_sleep(1);
                #pragma unroll
                for (int j = 1; j < 8; ++j)
                    if (ffbits(q[j])) q[j] = (it2 < 64) ? AL(rp + j) : ARMW(rp + j);
                bad = ffbits(q[1]) | ffbits(q[2]) | ffbits(q[3]) | ffbits(q[4])
                    | ffbits(q[5]) | ffbits(q[6]) | ffbits(q[7]);
            }
            #pragma unroll
            for (int j = 0; j < 4; ++j) {
                u64x2 v = {q[2 * j], q[2 * j + 1]};
                *(u64x2*)(hlds + ((lq * 4 + j) * 16 + prow) * 16) = v;
            }
        }
        __syncthreads();

        // MFMA: lane-contiguous A reads (conflict-free)
        f32x4 acc[2] = {};
        #pragma unroll
        for (int ks = 0; ks < 8; ++ks) {
            int ko = (kq * 8 + ks) * 4 + hi;
            short8 a = *(const short8*)(hlds + ko * 256 + l15 * 16);
            acc[0] = mfma16(a, wf[0][ks], acc[0]);
            acc[1] = mfma16(a, wf[1][ks], acc[1]);
        }
        #pragma unroll
        for (int ci = 0; ci < 2; ++ci)
            #pragma unroll
            for (int j = 0; j < 4; ++j)
                gl[kq][hi * 4 + j][cq * 32 + ci * 16 + l15] = acc[ci][j];
        __syncthreads();

        // update (t<512, one cell each) + packed publish via shfl
        if (t < 512) {
            float4 s = *(const float4*)&gl[0][urow][ujh * 4];
            #pragma unroll
            for (int k2 = 1; k2 < 4; ++k2) {
                float4 s2 = *(const float4*)&gl[k2][urow][ujh * 4];
                s.x += s2.x; s.y += s2.y; s.z += s2.z; s.w += s2.w;
            }
            float gi = s.x + bf2f(xv.x);
            float gf = s.y + bf2f(xv.y);
            float gg = s.z + bf2f(xv.z);
            float go = s.w + bf2f(xv.w);
            float it_ = sigm(gi), ft = sigm(gf), gt = tanh_(gg), ot = sigm(go);
            float cn = ft * creg + it_ * gt;
            float hn = ot * tanh_(cn);
            creg = cn;
            if (is_last && st == Tcc - 1) {
                size_t o = (size_t)(row0 + urow) * H_ + cb * 32 + ujh;
                outp[o] = hn;
                outp[(size_t)B_ * H_ + o] = cn;
            } else {
                unsigned hb = (unsigned)f2bf(hn);
                unsigned ob = __shfl_xor(hb, 1);
                unsigned v01 = (l & 1) ? (ob | (hb << 16)) : (hb | (ob << 16));
                unsigned v23 = __shfl_xor(v01, 2);
                if ((t & 3) == 0) {
                    u64 hw = (u64)v01 | ((u64)v23 << 32);
                    int dst = (st == Tcc - 1) ? 0 : st + 1;   // carry -> slot 0
                    u64* wp = hring + (size_t)dst * SLOTG
                            + (size_t)(row0 + urow) * 256 + cb * 8 + (ujh >> 2);
                    *(volatile u64*)wp = hw;   // fast path: shared XCD L2
                    (void)__hip_atomic_exchange(wp, hw, __ATOMIC_RELAXED,
                                                __HIP_MEMORY_SCOPE_AGENT); // LLC backup
                }
            }
        }
        // no trailing barrier: hlds reads done before barrier-2; gl
        // rewritten only after next barrier-1.
    }
    if (t < 512)
        cbuf[(size_t)(row0 + urow) * H_ + cb * 32 + ujh] = creg;
}

extern "C" void kernel_launch(void* const* d_in, const int* in_sizes, int n_in,
                              void* d_out, int out_size, void* d_ws, size_t ws_size,
                              hipStream_t stream) {
    const float* x = (const float*)d_in[0];
    const float* Wx[4] = {(const float*)d_in[1], (const float*)d_in[3],
                          (const float*)d_in[5], (const float*)d_in[7]};
    const float* Wh[4] = {(const float*)d_in[2], (const float*)d_in[4],
                          (const float*)d_in[6], (const float*)d_in[8]};
    const float* bx[4] = {(const float*)d_in[9],  (const float*)d_in[11],
                          (const float*)d_in[13], (const float*)d_in[15]};
    const float* bh[4] = {(const float*)d_in[10], (const float*)d_in[12],
                          (const float*)d_in[14], (const float*)d_in[16]};

    char* p = (char*)d_ws;
    auto take = [&](size_t bytes) {
        char* q = p; p += (bytes + 255) & ~(size_t)255; return q;
    };
    unsigned short* Winp = (unsigned short*)take((size_t)G4_ * 1024 * 2);
    unsigned short* Whp  = (unsigned short*)take((size_t)G4_ * 1024 * 2);
    float*          bias = (float*)take(G4_ * 4);
    float*          cbuf = (float*)take((size_t)B_ * H_ * 4);
    size_t fixed = (size_t)(p - (char*)d_ws) + SLOTG * 8 + 512;  // + ring slot 0
    // per-timestep: xb bf16 + xp bf16 + one h ring slot
    size_t per = (size_t)B_ * I_ * 2 + (size_t)B_ * G4_ * 2 + SLOTG * 8 + 768;
    size_t avail = ws_size > fixed ? ws_size - fixed : 0;
    int Tc = (int)(avail / per);
    if (Tc > T_) Tc = T_;
    if (Tc < 2) Tc = 2;                       // needs ~26 MB ws minimum
    unsigned short* xb    = (unsigned short*)take((size_t)Tc * B_ * I_ * 2);
    unsigned short* xpc   = (unsigned short*)take((size_t)Tc * B_ * G4_ * 2);
    u64*            hring = (u64*)take((size_t)(Tc + 1) * SLOTG * 8);

    pack_w8<<<dim3(16, 16, 8), 256, 0, stream>>>(
        Wx[0], Wx[1], Wx[2], Wx[3], Wh[0], Wh[1], Wh[2], Wh[3], Winp, Whp);
    pack_bias<<<16, 256, 0, stream>>>(bx[0], bh[0], bx[1], bh[1],
                                      bx[2], bh[2], bx[3], bh[3], bias);
    (void)hipMemsetAsync(hring, 0, SLOTG * 8, stream);   // slot 0 = h0 = zeros
    (void)hipMemsetAsync(cbuf, 0, (size_t)B_ * H_ * 4, stream);

    int t0 = 0;
    while (t0 < T_) {
        int rem = T_ - t0;
        int Tcc = (rem < Tc) ? rem : Tc;
        if (rem - Tcc == 1) Tcc -= 1;         // never leave a 1-step chunk
        int last = (t0 + Tcc >= T_) ? 1 : 0;
        convert_x<<<Tcc * 64, 256, 0, stream>>>(x, xb, t0, Tcc);
        gemm_xproj<<<dim3(16, 2 * Tcc), 256, 0, stream>>>(
            xb, Winp, bias, xpc, Tcc);
        (void)hipMemsetAsync(hring + SLOTG, 0xFF,
                             (size_t)Tcc * SLOTG * 8, stream);   // sentinels
        lstm_recur<<<256, 1024, 0, stream>>>(Whp, xpc, hring, cbuf,
                                             (float*)d_out, Tcc, last);
        t0 += Tcc;
    }
}